// Round 1
// baseline (185.903 us; speedup 1.0000x reference)
//
#include <hip/hip_runtime.h>

#define N_ROUTE 1152
#define C_IN    8
#define C_OUT   16
#define N_BATCH 256
#define N_CAPS  10
#define PPAD    17          // LDS row stride (coprime with 32 banks)
#define NPASS   (N_ROUTE / 64)

__global__ __launch_bounds__(256, 2)
void capsule_routing(const float* __restrict__ x,
                     const float* __restrict__ W,
                     float* __restrict__ out)
{
    __shared__ float P[N_ROUTE * PPAD];   // priors, padded rows
    __shared__ float red[64];             // 4 waves x 16 partial s
    __shared__ float redsc[8];            // softmax max/sum partials

    const int t   = threadIdx.x;
    const int bid = blockIdx.x;
    const int c   = bid >> 8;             // capsule
    const int b   = bid & 255;            // batch

    // ---------- Phase A: priors P[n][o] = sum_i x[b,n,i] * W[c,n,i,o] ----------
    {
        const int og = t & 3;             // o-group: o = og*4..og*4+3
        const int nl = t >> 2;            // 0..63
        const float* __restrict__ xb = x + (size_t)b * (N_ROUTE * C_IN);
        const float* __restrict__ Wc = W + (size_t)c * (N_ROUTE * C_IN * C_OUT);
        for (int p = 0; p < NPASS; ++p) {
            const int n = (p << 6) + nl;
            const float4 x0 = *reinterpret_cast<const float4*>(xb + n * C_IN);
            const float4 x1 = *reinterpret_cast<const float4*>(xb + n * C_IN + 4);
            const float xs[8] = {x0.x, x0.y, x0.z, x0.w, x1.x, x1.y, x1.z, x1.w};
            const float* __restrict__ wp = Wc + (size_t)n * (C_IN * C_OUT) + (og << 2);
            float4 acc = make_float4(0.f, 0.f, 0.f, 0.f);
            #pragma unroll
            for (int i = 0; i < 8; ++i) {
                const float4 w = *reinterpret_cast<const float4*>(wp + i * C_OUT);
                acc.x = fmaf(xs[i], w.x, acc.x);
                acc.y = fmaf(xs[i], w.y, acc.y);
                acc.z = fmaf(xs[i], w.z, acc.z);
                acc.w = fmaf(xs[i], w.w, acc.w);
            }
            const int base = n * PPAD + (og << 2);
            P[base + 0] = acc.x;
            P[base + 1] = acc.y;
            P[base + 2] = acc.z;
            P[base + 3] = acc.w;
        }
    }
    __syncthreads();

    // ---------- Routing: 3 iterations, logits scalar per n, in registers ----------
    const int lane  = t & 63;
    const int wid   = t >> 6;
    const int nrows = (t < 128) ? 5 : 4;  // thread owns n = t + 256k

    float lg[5];                           // logits for owned rows

    #pragma unroll
    for (int it = 0; it < 3; ++it) {
        float ek[5];
        float Zinv;
        if (it == 0) {
            #pragma unroll
            for (int k = 0; k < 5; ++k) ek[k] = 1.0f;
            Zinv = 1.0f / (float)N_ROUTE;         // softmax of zeros = uniform
        } else {
            // block max of logits
            float m = -1e30f;
            for (int k = 0; k < nrows; ++k) m = fmaxf(m, lg[k]);
            #pragma unroll
            for (int off = 32; off >= 1; off >>= 1)
                m = fmaxf(m, __shfl_xor(m, off));
            if (lane == 0) redsc[wid] = m;
            __syncthreads();
            m = fmaxf(fmaxf(redsc[0], redsc[1]), fmaxf(redsc[2], redsc[3]));
            // block sum of exp
            float zp = 0.f;
            for (int k = 0; k < nrows; ++k) { ek[k] = __expf(lg[k] - m); zp += ek[k]; }
            #pragma unroll
            for (int off = 32; off >= 1; off >>= 1)
                zp += __shfl_xor(zp, off);
            if (lane == 0) redsc[4 + wid] = zp;
            __syncthreads();
            Zinv = 1.0f / (redsc[4] + redsc[5] + redsc[6] + redsc[7]);
        }

        // s[o] = Zinv * sum_n e[n] * P[n][o]
        float sp[16];
        #pragma unroll
        for (int o = 0; o < 16; ++o) sp[o] = 0.f;
        for (int k = 0; k < nrows; ++k) {
            const int n = t + (k << 8);
            const float e = ek[k];
            const float* __restrict__ pr = &P[n * PPAD];
            #pragma unroll
            for (int o = 0; o < 16; ++o) sp[o] = fmaf(e, pr[o], sp[o]);
        }
        #pragma unroll
        for (int o = 0; o < 16; ++o) {
            float v = sp[o];
            #pragma unroll
            for (int off = 32; off >= 1; off >>= 1)
                v += __shfl_xor(v, off);
            if (lane == 0) red[(wid << 4) + o] = v;
        }
        __syncthreads();

        // every thread reconstructs s and squashes (replicated, broadcast reads)
        float vcur[16];
        float sq = 0.f;
        #pragma unroll
        for (int o = 0; o < 16; ++o) {
            const float s = (red[o] + red[16 + o] + red[32 + o] + red[48 + o]) * Zinv;
            vcur[o] = s;
            sq = fmaf(s, s, sq);
        }
        const float fac = sqrtf(sq) / (1.0f + sq);   // squash: t * sqrt(sq)/(1+sq)
        #pragma unroll
        for (int o = 0; o < 16; ++o) vcur[o] *= fac;

        if (it < 2) {
            // logits[n] += dot(P[n], v)
            for (int k = 0; k < nrows; ++k) {
                const int n = t + (k << 8);
                const float* __restrict__ pr = &P[n * PPAD];
                float d = 0.f;
                #pragma unroll
                for (int o = 0; o < 16; ++o) d = fmaf(pr[o], vcur[o], d);
                lg[k] = (it == 0) ? d : (lg[k] + d);
            }
            __syncthreads();   // protect red/redsc reuse next iteration
        } else {
            if (t < 16) out[((size_t)bid << 4) + t] = vcur[t];
        }
    }
}

extern "C" void kernel_launch(void* const* d_in, const int* in_sizes, int n_in,
                              void* d_out, int out_size, void* d_ws, size_t ws_size,
                              hipStream_t stream)
{
    const float* x   = (const float*)d_in[0];
    const float* W   = (const float*)d_in[1];
    float*       out = (float*)d_out;
    capsule_routing<<<dim3(N_CAPS * N_BATCH), dim3(256), 0, stream>>>(x, W, out);
}